// Round 30
// baseline (74.245 us; speedup 1.0000x reference)
//
#include <hip/hip_runtime.h>
#include <hip/hip_bf16.h>
#include <cstdint>

// MoE MLP fused forward. T=512, K=2 slots, E=32, H=512, I=512 (2I=1024).
// DEVICE DTYPES (probe-verified r20-r22): f32 tensors with bf16-exact values;
// output = full 262144 x f32 at d_out.
//
// r26-r29: mlp1 pinned at ~40us / ~1 TB/s HBM, invariant under wave count,
// segment count, and source-level prefetch. Shared property of all variants:
// B-fragment loads read 16 weight rows at 2KB stride (64B/row) -> fine-grain
// HBM scatter, ~1/6 DRAM efficiency (fill kernel in same trace: 6.9 TB/s;
// r22's sequential weight reads: 3.4 TB/s). r30: canonical LDS-staged GEMM —
// stage weight tiles with LONG SEQUENTIAL runs (1KB/instruction), fragments
// via ds_read_b128 from padded LDS (<=2-way conflicts, free). Natural k-order
// (no permutation). mlp2 keeps kz-split + partial buffers; fixed-order
// combine; no atomics -> bitwise deterministic.

#define MOE_E 32
#define MOE_H 512
#define MOE_I 512
#define MOE_2I 1024
#define MOE_CAP 1024
#define LDP 132   // 128 + 4 pad floats per LDS row

typedef __attribute__((ext_vector_type(8))) short s16x8;   // 8 bf16
typedef __attribute__((ext_vector_type(4))) float f32x4;   // 4 f32 acc

__device__ __forceinline__ s16x8 pack8(float4 f0, float4 f1) {
    union { unsigned int u[4]; s16x8 v; } r;
    r.u[0] = (__float_as_uint(f0.y) & 0xFFFF0000u) | (__float_as_uint(f0.x) >> 16);
    r.u[1] = (__float_as_uint(f0.w) & 0xFFFF0000u) | (__float_as_uint(f0.z) >> 16);
    r.u[2] = (__float_as_uint(f1.y) & 0xFFFF0000u) | (__float_as_uint(f1.x) >> 16);
    r.u[3] = (__float_as_uint(f1.w) & 0xFFFF0000u) | (__float_as_uint(f1.z) >> 16);
    return r.v;
}

// ---------------- route: bucket (token,slot) pairs by expert ----------------
__global__ __launch_bounds__(1024) void moe_route(const int* __restrict__ idx,
                                                  int* __restrict__ cnt,
                                                  int* __restrict__ lists) {
    __shared__ int scnt[MOE_E];
    const int p = threadIdx.x;
    if (p < MOE_E) scnt[p] = 0;
    __syncthreads();
    int e = idx[p];
    e = (e < 0) ? 0 : (e > MOE_E - 1 ? MOE_E - 1 : e);
    const int pos = atomicAdd(&scnt[e], 1);
    lists[e * MOE_CAP + pos] = p;
    __syncthreads();
    if (p < MOE_E) cnt[p] = scnt[p];
}

// ---- mlp1 (MFMA, LDS-staged): grid (16, E). Block: 64 w1-rows, full K. ----
// K-loop: 4 chunks of 128. Stage Bs[64][128] + As[32][128] (f32, padded),
// then 4 k-steps of 32: ds_read_b128 fragments -> bf16 pack -> MFMA.
__global__ __launch_bounds__(256) void moe_mlp1(
    const float* __restrict__ x, const float* __restrict__ w1,
    const float* __restrict__ b1, const int* __restrict__ cnt,
    const int* __restrict__ lists, float* __restrict__ t1) {
    __shared__ float Bs[64][LDP];
    __shared__ float As[32][LDP];
    const int e = blockIdx.y;
    const int ne = cnt[e];
    if (ne == 0) return;
    const int tid  = threadIdx.x;
    const int lane = tid & 63;
    const int wave = tid >> 6;
    const int n16  = lane & 15;
    const int k8   = lane >> 4;
    const int* lst = lists + e * MOE_CAP;
    const int cg = blockIdx.x * 64 + wave * 16 + n16;      // w1 row / t1 col
    const float bv = b1[e * MOE_2I + cg];
    const float* wbase = w1 + ((size_t)e * MOE_2I + blockIdx.x * 64) * MOE_H;

    for (int m0 = 0; m0 < ne; m0 += 32) {
        f32x4 acc0 = {0.f, 0.f, 0.f, 0.f};
        f32x4 acc1 = {0.f, 0.f, 0.f, 0.f};
        for (int kc = 0; kc < 4; ++kc) {
            __syncthreads();   // prior compute / prior tile done
            // stage Bs: 64 rows x 32 f4 = 2048 f4, 8 per thread (sequential runs)
            #pragma unroll
            for (int q = 0; q < 8; ++q) {
                const int i4  = tid + 256 * q;
                const int row = i4 >> 5;
                const int c4  = i4 & 31;
                const float4 v = *(const float4*)(wbase + (size_t)row * MOE_H
                                                  + kc * 128 + c4 * 4);
                *(float4*)(&Bs[row][c4 * 4]) = v;
            }
            // stage As: 32 token rows x 32 f4 = 1024 f4, 4 per thread
            #pragma unroll
            for (int q = 0; q < 4; ++q) {
                const int i4  = tid + 256 * q;
                const int row = i4 >> 5;
                const int c4  = i4 & 31;
                const int pm  = lst[min(m0 + row, ne - 1)];
                const float4 v = *(const float4*)(x + (size_t)(pm >> 1) * MOE_H
                                                  + kc * 128 + c4 * 4);
                *(float4*)(&As[row][c4 * 4]) = v;
            }
            __syncthreads();
            // 4 k-steps of 32
            #pragma unroll
            for (int ks = 0; ks < 4; ++ks) {
                const int ko = ks * 32 + k8 * 8;
                const float4 b0 = *(const float4*)(&Bs[wave * 16 + n16][ko]);
                const float4 b1v = *(const float4*)(&Bs[wave * 16 + n16][ko + 4]);
                const float4 a00 = *(const float4*)(&As[n16][ko]);
                const float4 a01 = *(const float4*)(&As[n16][ko + 4]);
                const float4 a10 = *(const float4*)(&As[n16 + 16][ko]);
                const float4 a11 = *(const float4*)(&As[n16 + 16][ko + 4]);
                const s16x8 BF = pack8(b0, b1v);
                acc0 = __builtin_amdgcn_mfma_f32_16x16x32_bf16(
                    pack8(a00, a01), BF, acc0, 0, 0, 0);
                acc1 = __builtin_amdgcn_mfma_f32_16x16x32_bf16(
                    pack8(a10, a11), BF, acc1, 0, 0, 0);
            }
        }
        const int mend = ne - m0;
        #pragma unroll
        for (int tile = 0; tile < 2; ++tile) {
            const f32x4 acc = tile ? acc1 : acc0;
            #pragma unroll
            for (int q = 0; q < 4; ++q) {
                const int mrow = tile * 16 + k8 * 4 + q;   // D: row=(l>>4)*4+q
                if (mrow < mend) {
                    const int p = lst[m0 + mrow];
                    t1[(size_t)p * MOE_2I + cg] = acc[q] + bv;
                }
            }
        }
    }
}

// ---- swiglu: h[pair][i] = swiglu(t1[pair][2i], t1[pair][2i+1]) -> f32 ----
__global__ __launch_bounds__(256) void moe_swiglu(
    const float* __restrict__ t1, float* __restrict__ hbuf) {
    const int tid  = threadIdx.x;
    const int pair = blockIdx.x * 2 + (tid >> 7);    // 512 blocks x 2 pairs
    const int i0   = (tid & 127) * 4;                // 4 h-cols
    const float4 v0 = *(const float4*)(t1 + (size_t)pair * MOE_2I + i0 * 2);
    const float4 v1 = *(const float4*)(t1 + (size_t)pair * MOE_2I + i0 * 2 + 4);
    float g0 = v0.x, l0 = v0.y, g1 = v0.z, l1 = v0.w;
    float g2 = v1.x, l2 = v1.y, g3 = v1.z, l3 = v1.w;
    g0 = fminf(g0, 7.0f); l0 = fminf(fmaxf(l0, -7.0f), 7.0f);
    g1 = fminf(g1, 7.0f); l1 = fminf(fmaxf(l1, -7.0f), 7.0f);
    g2 = fminf(g2, 7.0f); l2 = fminf(fmaxf(l2, -7.0f), 7.0f);
    g3 = fminf(g3, 7.0f); l3 = fminf(fmaxf(l3, -7.0f), 7.0f);
    float4 h;
    h.x = g0 / (1.0f + expf(-1.702f * g0)) * (l0 + 1.0f);
    h.y = g1 / (1.0f + expf(-1.702f * g1)) * (l1 + 1.0f);
    h.z = g2 / (1.0f + expf(-1.702f * g2)) * (l2 + 1.0f);
    h.w = g3 / (1.0f + expf(-1.702f * g3)) * (l3 + 1.0f);
    *(float4*)(hbuf + (size_t)pair * MOE_I + i0) = h;
}

// ---- mlp2 partial (MFMA, LDS-staged): grid (8, E, 2=kz). ----
// Block: 64 w2-rows, K-half 256 (2 chunks of 128). Partials -> pop[kz].
__global__ __launch_bounds__(256) void moe_mlp2(
    const float* __restrict__ hbuf, const float* __restrict__ w2,
    const float* __restrict__ b2, const int* __restrict__ cnt,
    const int* __restrict__ lists, float* __restrict__ pop) {
    __shared__ float Bs[64][LDP];
    __shared__ float As[32][LDP];
    const int e = blockIdx.y;
    const int ne = cnt[e];
    if (ne == 0) return;
    const int kz = blockIdx.z;
    const int tid  = threadIdx.x;
    const int lane = tid & 63;
    const int wave = tid >> 6;
    const int n16  = lane & 15;
    const int k8   = lane >> 4;
    const int* lst = lists + e * MOE_CAP;
    const int c = blockIdx.x * 64 + wave * 16 + n16;       // out col 0..511
    const float bv = (kz == 0) ? b2[e * MOE_H + c] : 0.0f;
    const float* wbase = w2 + ((size_t)e * MOE_H + blockIdx.x * 64) * MOE_I
                         + kz * 256;
    float* po = pop + (size_t)kz * MOE_CAP * MOE_H;

    for (int m0 = 0; m0 < ne; m0 += 32) {
        f32x4 acc0 = {0.f, 0.f, 0.f, 0.f};
        f32x4 acc1 = {0.f, 0.f, 0.f, 0.f};
        for (int kc = 0; kc < 2; ++kc) {
            __syncthreads();
            #pragma unroll
            for (int q = 0; q < 8; ++q) {
                const int i4  = tid + 256 * q;
                const int row = i4 >> 5;
                const int c4  = i4 & 31;
                const float4 v = *(const float4*)(wbase + (size_t)row * MOE_I
                                                  + kc * 128 + c4 * 4);
                *(float4*)(&Bs[row][c4 * 4]) = v;
            }
            #pragma unroll
            for (int q = 0; q < 4; ++q) {
                const int i4  = tid + 256 * q;
                const int row = i4 >> 5;
                const int c4  = i4 & 31;
                const int pm  = lst[min(m0 + row, ne - 1)];
                const float4 v = *(const float4*)(hbuf + (size_t)pm * MOE_I
                                                  + kz * 256 + kc * 128 + c4 * 4);
                *(float4*)(&As[row][c4 * 4]) = v;
            }
            __syncthreads();
            #pragma unroll
            for (int ks = 0; ks < 4; ++ks) {
                const int ko = ks * 32 + k8 * 8;
                const float4 b0 = *(const float4*)(&Bs[wave * 16 + n16][ko]);
                const float4 b1v = *(const float4*)(&Bs[wave * 16 + n16][ko + 4]);
                const float4 a00 = *(const float4*)(&As[n16][ko]);
                const float4 a01 = *(const float4*)(&As[n16][ko + 4]);
                const float4 a10 = *(const float4*)(&As[n16 + 16][ko]);
                const float4 a11 = *(const float4*)(&As[n16 + 16][ko + 4]);
                const s16x8 BF = pack8(b0, b1v);
                acc0 = __builtin_amdgcn_mfma_f32_16x16x32_bf16(
                    pack8(a00, a01), BF, acc0, 0, 0, 0);
                acc1 = __builtin_amdgcn_mfma_f32_16x16x32_bf16(
                    pack8(a10, a11), BF, acc1, 0, 0, 0);
            }
        }
        const int mend = ne - m0;
        #pragma unroll
        for (int tile = 0; tile < 2; ++tile) {
            const f32x4 acc = tile ? acc1 : acc0;
            #pragma unroll
            for (int q = 0; q < 4; ++q) {
                const int mrow = tile * 16 + k8 * 4 + q;
                if (mrow < mend) {
                    const int p = lst[m0 + mrow];
                    po[(size_t)p * MOE_H + c] = acc[q] + bv;
                }
            }
        }
    }
}

// ---- combine: out[t,c] = ew0*(p0a+p0b) + ew1*(p1a+p1b), fixed order ----
__global__ __launch_bounds__(256) void MoEMLPFused_74191265071207_kernel(
    const float* __restrict__ pop, const float* __restrict__ ew,
    float* __restrict__ out) {
    const int o = blockIdx.x * 256 + threadIdx.x;   // < 262144
    const int t = o >> 9;
    const int c = o & 511;
    const float* pa = pop;
    const float* pb = pop + (size_t)MOE_CAP * MOE_H;
    const float s0 = pa[(size_t)(2 * t + 0) * MOE_H + c]
                   + pb[(size_t)(2 * t + 0) * MOE_H + c];
    const float s1 = pa[(size_t)(2 * t + 1) * MOE_H + c]
                   + pb[(size_t)(2 * t + 1) * MOE_H + c];
    out[o] = ew[2 * t + 0] * s0 + ew[2 * t + 1] * s1;
}

extern "C" void kernel_launch(void* const* d_in, const int* in_sizes, int n_in,
                              void* d_out, int out_size, void* d_ws, size_t ws_size,
                              hipStream_t stream) {
    const float* x   = (const float*)d_in[0];
    const int*   idx = (const int*)d_in[1];
    const float* ew  = (const float*)d_in[2];
    const float* w1  = (const float*)d_in[3];
    const float* b1  = (const float*)d_in[4];
    const float* w2  = (const float*)d_in[5];
    const float* b2  = (const float*)d_in[6];
    float* out = (float*)d_out;

    // ws: cnt 256B | lists 128KB | t1 4MB | hbuf 2MB | pop 2x2MB (~10.2MB)
    char* ws = (char*)d_ws;
    int* cnt    = (int*)ws;
    int* lists  = (int*)(ws + 256);
    float* t1   = (float*)(ws + 256 + MOE_E * MOE_CAP * 4);
    float* hbuf = t1 + (size_t)MOE_CAP * MOE_2I;
    float* pop  = hbuf + (size_t)MOE_CAP * MOE_I;

    moe_route<<<1, 1024, 0, stream>>>(idx, cnt, lists);
    moe_mlp1<<<dim3(16, MOE_E), 256, 0, stream>>>(x, w1, b1, cnt, lists, t1);
    moe_swiglu<<<512, 256, 0, stream>>>(t1, hbuf);
    moe_mlp2<<<dim3(8, MOE_E, 2), 256, 0, stream>>>(hbuf, w2, b2, cnt, lists, pop);
    MoEMLPFused_74191265071207_kernel<<<(512 * MOE_H) / 256, 256, 0, stream>>>(
        pop, ew, out);
}

// Round 31
// 59.266 us; speedup vs baseline: 1.2527x; 1.2527x over previous
//
#include <hip/hip_runtime.h>
#include <hip/hip_bf16.h>
#include <cstdint>

// MoE MLP fused forward. T=512, K=2 slots, E=32, H=512, I=512 (2I=1024).
// DEVICE DTYPES (probe-verified r20-r22): f32 tensors with bf16-exact values;
// output = full 262144 x f32 at d_out.
//
// r26-r30: mlp1 pinned at ~1 TB/s under FOUR different structures. Model that
// fits all data: VGPR-mediated loads cap in-flight bytes (~2-3 KB/CU) far
// below the ~22 KB needed to cover ~900cy HBM latency (L3 is wiped between
// replays by the harness's 268MB ws fills, so weights are HBM-cold).
// r31: global_load_lds staging (no VGPR round-trip, deep vmcnt pipeline).
// LDS unit-interleaved layout [kquad][row][16B]: glds writes linearly
// (lane x 16B) with per-lane global sources implementing the layout; ds_read
// fragments hit consecutive units (conflict-free). B staged once per block;
// K split x4 over blockIdx.z; partial buffers + fixed-order sums -> bitwise
// deterministic.

#define MOE_E 32
#define MOE_H 512
#define MOE_I 512
#define MOE_2I 1024
#define MOE_CAP 1024

typedef __attribute__((ext_vector_type(8))) short s16x8;   // 8 bf16
typedef __attribute__((ext_vector_type(4))) float f32x4;   // 4 f32 acc

#define GLDS16(g, l)  __builtin_amdgcn_global_load_lds(                        \
    (const __attribute__((address_space(1))) unsigned int*)(g),                \
    (__attribute__((address_space(3))) unsigned int*)(l), 16, 0, 0)

__device__ __forceinline__ s16x8 pack8(float4 f0, float4 f1) {
    union { unsigned int u[4]; s16x8 v; } r;
    r.u[0] = (__float_as_uint(f0.y) & 0xFFFF0000u) | (__float_as_uint(f0.x) >> 16);
    r.u[1] = (__float_as_uint(f0.w) & 0xFFFF0000u) | (__float_as_uint(f0.z) >> 16);
    r.u[2] = (__float_as_uint(f1.y) & 0xFFFF0000u) | (__float_as_uint(f1.x) >> 16);
    r.u[3] = (__float_as_uint(f1.w) & 0xFFFF0000u) | (__float_as_uint(f1.z) >> 16);
    return r.v;
}

// ---------------- route: bucket (token,slot) pairs by expert ----------------
__global__ __launch_bounds__(1024) void moe_route(const int* __restrict__ idx,
                                                  int* __restrict__ cnt,
                                                  int* __restrict__ lists) {
    __shared__ int scnt[MOE_E];
    const int p = threadIdx.x;
    if (p < MOE_E) scnt[p] = 0;
    __syncthreads();
    int e = idx[p];
    e = (e < 0) ? 0 : (e > MOE_E - 1 ? MOE_E - 1 : e);
    const int pos = atomicAdd(&scnt[e], 1);
    lists[e * MOE_CAP + pos] = p;
    __syncthreads();
    if (p < MOE_E) cnt[p] = scnt[p];
}

// ---- mlp1 partial (MFMA, glds-staged): grid (16, E, 4=kz), 256 thr. ----
// Block: 64 w1-rows x K-chunk 128. LDS: Bs units [32 kq][64 row] (32KB),
// As units [32 kq][32 row] (16KB). Partial t1 (+bias kz=0) -> t1p[kz].
__global__ __launch_bounds__(256) void moe_mlp1(
    const float* __restrict__ x, const float* __restrict__ w1,
    const float* __restrict__ b1, const int* __restrict__ cnt,
    const int* __restrict__ lists, float* __restrict__ t1p) {
    __shared__ float Bs[32 * 64 * 4];   // unit u=(q*64+r): floats u*4..u*4+3
    __shared__ float As[32 * 32 * 4];   // unit u=(q*32+r)
    const int e = blockIdx.y;
    const int ne = cnt[e];
    if (ne == 0) return;
    const int kz = blockIdx.z;
    const int tid  = threadIdx.x;
    const int lane = tid & 63;
    const int wave = tid >> 6;
    const int n16  = lane & 15;
    const int k8   = lane >> 4;
    const int* lst = lists + e * MOE_CAP;
    const int cg = blockIdx.x * 64 + wave * 16 + n16;      // w1 row / t1 col
    const float bv = (kz == 0) ? b1[e * MOE_2I + cg] : 0.0f;
    const float* wbase = w1 + ((size_t)e * MOE_2I + blockIdx.x * 64) * MOE_H
                         + kz * 128;
    float* t1 = t1p + (size_t)kz * MOE_CAP * MOE_2I;

    // Stage Bs once: 2048 units, 8 glds/thread. unit u -> src row u&63, quad u>>6.
    #pragma unroll
    for (int j = 0; j < 8; ++j) {
        const int u = (j * 4 + wave) * 64 + lane;
        const int q = u >> 6, r = u & 63;
        GLDS16(wbase + (size_t)r * MOE_H + q * 4, Bs + (size_t)(j * 4 + wave) * 256);
    }

    for (int m0 = 0; m0 < ne; m0 += 32) {
        __syncthreads();   // prior-iter LDS readers done (also drains Bs iter 1)
        // Stage As: 1024 units, 4 glds/thread. unit u -> row u&31, quad u>>5.
        #pragma unroll
        for (int j = 0; j < 4; ++j) {
            const int u = (j * 4 + wave) * 64 + lane;
            const int q = u >> 5, r = u & 31;
            const int pm = lst[min(m0 + r, ne - 1)];
            GLDS16(x + (size_t)(pm >> 1) * MOE_H + kz * 128 + q * 4,
                   As + (size_t)(j * 4 + wave) * 256);
        }
        __syncthreads();   // vmcnt(0) drain: Bs + As visible

        f32x4 acc0 = {0.f, 0.f, 0.f, 0.f};
        f32x4 acc1 = {0.f, 0.f, 0.f, 0.f};
        #pragma unroll
        for (int ks = 0; ks < 4; ++ks) {
            const int qB = ks * 8 + k8 * 2;
            const float4 B0  = *(const float4*)(Bs + 4 * (qB * 64 + wave * 16 + n16));
            const float4 B1  = *(const float4*)(Bs + 4 * ((qB + 1) * 64 + wave * 16 + n16));
            const float4 A00 = *(const float4*)(As + 4 * (qB * 32 + n16));
            const float4 A01 = *(const float4*)(As + 4 * ((qB + 1) * 32 + n16));
            const float4 A10 = *(const float4*)(As + 4 * (qB * 32 + 16 + n16));
            const float4 A11 = *(const float4*)(As + 4 * ((qB + 1) * 32 + 16 + n16));
            const s16x8 BF = pack8(B0, B1);
            acc0 = __builtin_amdgcn_mfma_f32_16x16x32_bf16(pack8(A00, A01), BF, acc0, 0, 0, 0);
            acc1 = __builtin_amdgcn_mfma_f32_16x16x32_bf16(pack8(A10, A11), BF, acc1, 0, 0, 0);
        }
        const int mend = ne - m0;
        #pragma unroll
        for (int tile = 0; tile < 2; ++tile) {
            const f32x4 acc = tile ? acc1 : acc0;
            #pragma unroll
            for (int q = 0; q < 4; ++q) {
                const int mrow = tile * 16 + k8 * 4 + q;   // D: row=(l>>4)*4+q
                if (mrow < mend) {
                    const int p = lst[m0 + mrow];
                    t1[(size_t)p * MOE_2I + cg] = acc[q] + bv;
                }
            }
        }
    }
}

// ---- swiglu: t1 = sum of 4 partials; even col gate, odd lin -> hbuf f32 ----
__global__ __launch_bounds__(256) void moe_swiglu(
    const float* __restrict__ t1p, float* __restrict__ hbuf) {
    const int tid  = threadIdx.x;
    const int pair = blockIdx.x * 2 + (tid >> 7);    // 512 blocks x 2 pairs
    const int i0   = (tid & 127) * 4;
    float4 s0 = {0.f, 0.f, 0.f, 0.f}, s1 = {0.f, 0.f, 0.f, 0.f};
    #pragma unroll
    for (int kzi = 0; kzi < 4; ++kzi) {
        const float* b = t1p + (size_t)kzi * MOE_CAP * MOE_2I
                       + (size_t)pair * MOE_2I + i0 * 2;
        const float4 v0 = *(const float4*)b;
        const float4 v1 = *(const float4*)(b + 4);
        s0.x += v0.x; s0.y += v0.y; s0.z += v0.z; s0.w += v0.w;
        s1.x += v1.x; s1.y += v1.y; s1.z += v1.z; s1.w += v1.w;
    }
    float g0 = s0.x, l0 = s0.y, g1 = s0.z, l1 = s0.w;
    float g2 = s1.x, l2 = s1.y, g3 = s1.z, l3 = s1.w;
    g0 = fminf(g0, 7.0f); l0 = fminf(fmaxf(l0, -7.0f), 7.0f);
    g1 = fminf(g1, 7.0f); l1 = fminf(fmaxf(l1, -7.0f), 7.0f);
    g2 = fminf(g2, 7.0f); l2 = fminf(fmaxf(l2, -7.0f), 7.0f);
    g3 = fminf(g3, 7.0f); l3 = fminf(fmaxf(l3, -7.0f), 7.0f);
    float4 h;
    h.x = g0 / (1.0f + expf(-1.702f * g0)) * (l0 + 1.0f);
    h.y = g1 / (1.0f + expf(-1.702f * g1)) * (l1 + 1.0f);
    h.z = g2 / (1.0f + expf(-1.702f * g2)) * (l2 + 1.0f);
    h.w = g3 / (1.0f + expf(-1.702f * g3)) * (l3 + 1.0f);
    *(float4*)(hbuf + (size_t)pair * MOE_I + i0) = h;
}

// ---- mlp2 partial (MFMA, glds-staged): grid (8, E, 4=kz). ----
__global__ __launch_bounds__(256) void moe_mlp2(
    const float* __restrict__ hbuf, const float* __restrict__ w2,
    const float* __restrict__ b2, const int* __restrict__ cnt,
    const int* __restrict__ lists, float* __restrict__ pop) {
    __shared__ float Bs[32 * 64 * 4];
    __shared__ float As[32 * 32 * 4];
    const int e = blockIdx.y;
    const int ne = cnt[e];
    if (ne == 0) return;
    const int kz = blockIdx.z;
    const int tid  = threadIdx.x;
    const int lane = tid & 63;
    const int wave = tid >> 6;
    const int n16  = lane & 15;
    const int k8   = lane >> 4;
    const int* lst = lists + e * MOE_CAP;
    const int c = blockIdx.x * 64 + wave * 16 + n16;       // out col 0..511
    const float bv = (kz == 0) ? b2[e * MOE_H + c] : 0.0f;
    const float* wbase = w2 + ((size_t)e * MOE_H + blockIdx.x * 64) * MOE_I
                         + kz * 128;
    float* po = pop + (size_t)kz * MOE_CAP * MOE_H;

    #pragma unroll
    for (int j = 0; j < 8; ++j) {
        const int u = (j * 4 + wave) * 64 + lane;
        const int q = u >> 6, r = u & 63;
        GLDS16(wbase + (size_t)r * MOE_I + q * 4, Bs + (size_t)(j * 4 + wave) * 256);
    }

    for (int m0 = 0; m0 < ne; m0 += 32) {
        __syncthreads();
        #pragma unroll
        for (int j = 0; j < 4; ++j) {
            const int u = (j * 4 + wave) * 64 + lane;
            const int q = u >> 5, r = u & 31;
            const int pm = lst[min(m0 + r, ne - 1)];
            GLDS16(hbuf + (size_t)pm * MOE_I + kz * 128 + q * 4,
                   As + (size_t)(j * 4 + wave) * 256);
        }
        __syncthreads();

        f32x4 acc0 = {0.f, 0.f, 0.f, 0.f};
        f32x4 acc1 = {0.f, 0.f, 0.f, 0.f};
        #pragma unroll
        for (int ks = 0; ks < 4; ++ks) {
            const int qB = ks * 8 + k8 * 2;
            const float4 B0  = *(const float4*)(Bs + 4 * (qB * 64 + wave * 16 + n16));
            const float4 B1  = *(const float4*)(Bs + 4 * ((qB + 1) * 64 + wave * 16 + n16));
            const float4 A00 = *(const float4*)(As + 4 * (qB * 32 + n16));
            const float4 A01 = *(const float4*)(As + 4 * ((qB + 1) * 32 + n16));
            const float4 A10 = *(const float4*)(As + 4 * (qB * 32 + 16 + n16));
            const float4 A11 = *(const float4*)(As + 4 * ((qB + 1) * 32 + 16 + n16));
            const s16x8 BF = pack8(B0, B1);
            acc0 = __builtin_amdgcn_mfma_f32_16x16x32_bf16(pack8(A00, A01), BF, acc0, 0, 0, 0);
            acc1 = __builtin_amdgcn_mfma_f32_16x16x32_bf16(pack8(A10, A11), BF, acc1, 0, 0, 0);
        }
        const int mend = ne - m0;
        #pragma unroll
        for (int tile = 0; tile < 2; ++tile) {
            const f32x4 acc = tile ? acc1 : acc0;
            #pragma unroll
            for (int q = 0; q < 4; ++q) {
                const int mrow = tile * 16 + k8 * 4 + q;
                if (mrow < mend) {
                    const int p = lst[m0 + mrow];
                    po[(size_t)p * MOE_H + c] = acc[q] + bv;
                }
            }
        }
    }
}

// ---- combine: out[t,c] = ew0*SUM4 pop[.,2t,c] + ew1*SUM4 pop[.,2t+1,c] ----
__global__ __launch_bounds__(256) void MoEMLPFused_74191265071207_kernel(
    const float* __restrict__ pop, const float* __restrict__ ew,
    float* __restrict__ out) {
    const int o = blockIdx.x * 256 + threadIdx.x;   // < 262144
    const int t = o >> 9;
    const int c = o & 511;
    float s0 = 0.f, s1 = 0.f;
    #pragma unroll
    for (int kzi = 0; kzi < 4; ++kzi) {
        const float* pb = pop + (size_t)kzi * MOE_CAP * MOE_H;
        s0 += pb[(size_t)(2 * t + 0) * MOE_H + c];
        s1 += pb[(size_t)(2 * t + 1) * MOE_H + c];
    }
    out[o] = ew[2 * t + 0] * s0 + ew[2 * t + 1] * s1;
}

extern "C" void kernel_launch(void* const* d_in, const int* in_sizes, int n_in,
                              void* d_out, int out_size, void* d_ws, size_t ws_size,
                              hipStream_t stream) {
    const float* x   = (const float*)d_in[0];
    const int*   idx = (const int*)d_in[1];
    const float* ew  = (const float*)d_in[2];
    const float* w1  = (const float*)d_in[3];
    const float* b1  = (const float*)d_in[4];
    const float* w2  = (const float*)d_in[5];
    const float* b2  = (const float*)d_in[6];
    float* out = (float*)d_out;

    // ws: cnt 256B | lists 128KB | t1p 4x4MB | hbuf 2MB | pop 4x2MB (~26.2MB)
    char* ws = (char*)d_ws;
    int* cnt    = (int*)ws;
    int* lists  = (int*)(ws + 256);
    float* t1p  = (float*)(ws + 256 + MOE_E * MOE_CAP * 4);
    float* hbuf = t1p + 4u * MOE_CAP * MOE_2I;
    float* pop  = hbuf + (size_t)MOE_CAP * MOE_I;

    moe_route<<<1, 1024, 0, stream>>>(idx, cnt, lists);
    moe_mlp1<<<dim3(16, MOE_E, 4), 256, 0, stream>>>(x, w1, b1, cnt, lists, t1p);
    moe_swiglu<<<512, 256, 0, stream>>>(t1p, hbuf);
    moe_mlp2<<<dim3(8, MOE_E, 4), 256, 0, stream>>>(hbuf, w2, b2, cnt, lists, pop);
    MoEMLPFused_74191265071207_kernel<<<(512 * MOE_H) / 256, 256, 0, stream>>>(
        pop, ew, out);
}